// Round 11
// baseline (95.197 us; speedup 1.0000x reference)
//
#include <hip/hip_runtime.h>
#include <hip/hip_bf16.h>
#include <stdint.h>

#define GAT_ALPHA 0.2f
#define LOG2E 1.4426950408889634f

typedef __attribute__((ext_vector_type(8))) short bf16x8;
typedef __attribute__((ext_vector_type(8))) unsigned short ushort8;
typedef __attribute__((ext_vector_type(4))) float f32x4;
typedef __attribute__((ext_vector_type(4))) unsigned int u32x4;

#if __has_builtin(__builtin_amdgcn_exp2f)
#define EXP2F(x) __builtin_amdgcn_exp2f(x)
#else
#define EXP2F(x) exp2f(x)
#endif

// D.lo = bf16(a), D.hi = bf16(b)  (r6-validated)
static __device__ __forceinline__ unsigned int cvt_pk_bf16(float a, float b) {
    unsigned int r;
    asm("v_cvt_pk_bf16_f32 %0, %1, %2" : "=v"(r) : "v"(a), "v"(b));
    return r;
}

// async global->LDS, 16B/lane; dest = wave-uniform base + lane*16 (m104),
// source is PER-LANE (m173 pre-swizzled-source pattern)
static __device__ __forceinline__ void gl16(const void* g, void* l) {
    __builtin_amdgcn_global_load_lds((const __attribute__((address_space(1))) void*)g,
                                     (__attribute__((address_space(3))) void*)l, 16, 0, 0);
}

// ---------------- K0: pack adjacency int32 -> bitmask (validated r1) -------
__global__ __launch_bounds__(256) void k_pack_adj(const int* __restrict__ adj,
                                                  unsigned long long* __restrict__ packed,
                                                  int nwords) {
    int gid = blockIdx.x * 256 + threadIdx.x;
    int wid = gid >> 6;               // one 64-bit word per wave
    int lane = threadIdx.x & 63;
    if (wid >= nwords) return;
    int v = adj[(size_t)wid * 64 + lane];
    unsigned long long m = __ballot(v > 0);
    if (lane == 0) packed[wid] = m;
}

// ---------------- K0b: W [8][256][32] f32 -> wbfT [8][32][256] bf16 (r9) ---
__global__ __launch_bounds__(256) void k_cvtW(const float* __restrict__ W,
                                              unsigned short* __restrict__ wbfT) {
    int idx = (blockIdx.x * 256 + threadIdx.x) * 8;   // over 65536 elements
    int hd = idx >> 8;                                 // head*32 + d
    int i0 = idx & 255;
    int hh = hd >> 5, dd = hd & 31;
    float v[8];
    #pragma unroll
    for (int k = 0; k < 8; ++k) v[k] = W[((size_t)hh * 256 + i0 + k) * 32 + dd];
    u32x4 o = { cvt_pk_bf16(v[0], v[1]), cvt_pk_bf16(v[2], v[3]),
                cvt_pk_bf16(v[4], v[5]), cvt_pk_bf16(v[6], v[7]) };
    *(u32x4*)&wbfT[idx] = o;
}

// ---------------- K1: Wh via bf16 MFMA (validated r9) ----------------------
__global__ __launch_bounds__(256) void k_wh2(const float* __restrict__ hmat,      // [4096][256]
                                             const unsigned short* __restrict__ wbfT, // [8][32][256]
                                             const float* __restrict__ avec,      // [8][64]
                                             float* __restrict__ wh1s,            // [8][4096] *log2e
                                             float* __restrict__ wh2s,            // [8][4096] *log2e
                                             unsigned short* __restrict__ whT) {  // [8][32][4096]
    const int head = blockIdx.y;
    const int nbase = blockIdx.x * 64;
    const int t = threadIdx.x, w = t >> 6, lane = t & 63;
    const int r = lane & 15, q = lane >> 4;
    const int node0 = nbase + w * 16;

    f32x4 acc0 = {0.f, 0.f, 0.f, 0.f};
    f32x4 acc1 = {0.f, 0.f, 0.f, 0.f};
    const float* arow = &hmat[(size_t)(node0 + r) * 256];
    const unsigned short* b0p = &wbfT[((size_t)head * 32 + r) * 256];
    const unsigned short* b1p = b0p + 16 * 256;
    #pragma unroll
    for (int kt = 0; kt < 8; ++kt) {
        const int ko = kt * 32 + q * 8;
        float4 h0 = *(const float4*)&arow[ko];
        float4 h1 = *(const float4*)&arow[ko + 4];
        u32x4 ap = { cvt_pk_bf16(h0.x, h0.y), cvt_pk_bf16(h0.z, h0.w),
                     cvt_pk_bf16(h1.x, h1.y), cvt_pk_bf16(h1.z, h1.w) };
        bf16x8 af = __builtin_bit_cast(bf16x8, ap);
        bf16x8 b0 = *(const bf16x8*)&b0p[ko];
        bf16x8 b1 = *(const bf16x8*)&b1p[ko];
        acc0 = __builtin_amdgcn_mfma_f32_16x16x32_bf16(af, b0, acc0, 0, 0, 0);
        acc1 = __builtin_amdgcn_mfma_f32_16x16x32_bf16(af, b1, acc1, 0, 0, 0);
    }
    u32x4 pk = { cvt_pk_bf16(acc0[0], acc0[1]), cvt_pk_bf16(acc0[2], acc0[3]),
                 cvt_pk_bf16(acc1[0], acc1[1]), cvt_pk_bf16(acc1[2], acc1[3]) };
    unsigned long long lo = ((unsigned long long)pk[1] << 32) | pk[0];
    unsigned long long hi = ((unsigned long long)pk[3] << 32) | pk[2];
    *(unsigned long long*)&whT[((size_t)head * 32 + r) * 4096 + node0 + q * 4] = lo;
    *(unsigned long long*)&whT[((size_t)head * 32 + 16 + r) * 4096 + node0 + q * 4] = hi;

    float a1lo = avec[head * 64 + r],      a1hi = avec[head * 64 + 16 + r];
    float a2lo = avec[head * 64 + 32 + r], a2hi = avec[head * 64 + 48 + r];
    f32x4 d1, d2;
    #pragma unroll
    for (int i = 0; i < 4; ++i) {
        d1[i] = fmaf(acc0[i], a1lo, acc1[i] * a1hi);
        d2[i] = fmaf(acc0[i], a2lo, acc1[i] * a2hi);
    }
    #pragma unroll
    for (int s = 1; s < 16; s <<= 1) {
        #pragma unroll
        for (int i = 0; i < 4; ++i) {
            d1[i] += __shfl_xor(d1[i], s);
            d2[i] += __shfl_xor(d2[i], s);
        }
    }
    if (r == 0) {
        f32x4 o1 = d1 * LOG2E, o2 = d2 * LOG2E;
        *(f32x4*)&wh1s[(size_t)head * 4096 + node0 + q * 4] = o1;
        *(f32x4*)&wh2s[(size_t)head * 4096 + node0 + q * 4] = o2;
    }
}

// ---------------- K2: fused masked softmax + PV via bf16 MFMA --------------
// 16-row blocks (grid 2048 = 8 blocks/CU -> 32 waves/CU), 4 waves share a
// 128-j double-buffered whT window; wave w owns sub-slice j = w*32 of each
// window (r10's kk := w), 32 steps. gl16 staging with r10's pre-swizzled
// source (phys slot p of row d holds logical slot p^(d&7)); reads use the
// same XOR -> both sides conflict-free. LDS ~17.2KB.
__global__ __launch_bounds__(256, 8) void k_attn(const unsigned long long* __restrict__ adj64, // [4096][64]
                                                 const float* __restrict__ wh1s,
                                                 const float* __restrict__ wh2s,
                                                 const unsigned short* __restrict__ whT,
                                                 float* __restrict__ out) {                    // [4096][256]
    const int head = blockIdx.y;
    const int rowbase = blockIdx.x * 16;
    const int t = threadIdx.x;
    const int w = t >> 6;        // j sub-slice within window / staging quarter
    const int lane = t & 63;
    const int r = lane & 15;     // MFMA A row / B col
    const int q = lane >> 4;     // k-quarter
    const int row = rowbase + r;

    __shared__ unsigned short whTl[2][32][128] __attribute__((aligned(16)));
    __shared__ float wh2t[2][128];
    __shared__ float wmxb[4];

    // pre-swizzled per-lane gl16 sources: this thread's 2 slots per step
    const unsigned short* gsrc[2];
    #pragma unroll
    for (int c = 0; c < 2; ++c) {
        int S = w * 128 + c * 64 + lane;   // linear 16B slot in tile
        int d = S >> 4, p = S & 15;
        int ls = p ^ (d & 7);              // logical slot stored at phys p
        gsrc[c] = whT + ((size_t)(head * 32 + d)) * 4096 + ls * 8;
    }
    const float* wh2p = &wh2s[(size_t)head * 4096];

    // prologue: stage step 0 into buf 0
    #pragma unroll
    for (int c = 0; c < 2; ++c)
        gl16(gsrc[c], ((unsigned short*)whTl[0]) + w * 1024 + c * 512);
    if (t < 32) *(float4*)&wh2t[0][t * 4] = *(const float4*)&wh2p[t * 4];

    // per-head max of wh2 (r5/r10-validated prepass)
    float lm = -INFINITY;
    #pragma unroll
    for (int kk = 0; kk < 4; ++kk) {
        float4 v = *(const float4*)&wh2p[kk * 1024 + t * 4];
        lm = fmaxf(fmaxf(lm, fmaxf(v.x, v.y)), fmaxf(v.z, v.w));
    }
    #pragma unroll
    for (int s = 1; s < 64; s <<= 1) lm = fmaxf(lm, __shfl_xor(lm, s));
    if (lane == 0) wmxb[w] = lm;
    __syncthreads();   // wmxb ready; stage-0 drained (vmcnt before barrier)
    const float wm = fmaxf(fmaxf(wmxb[0], wmxb[1]), fmaxf(wmxb[2], wmxb[3]));

    // per-row constants (r6-validated math, log2-scaled domain)
    const float wh1 = wh1s[(size_t)head * 4096 + row];
    const float sm0 = wh1 + wm;
    const float m = fmaxf(sm0, GAT_ALPHA * sm0);
    const float wh1m = wh1 - m;
    const float c2 = GAT_ALPHA * wh1 - m;

    f32x4 acc0 = {0.f, 0.f, 0.f, 0.f};
    f32x4 acc1 = {0.f, 0.f, 0.f, 0.f};
    f32x4 accd = {0.f, 0.f, 0.f, 0.f};

    const u32x4 onesu = {0x3F803F80u, 0x3F803F80u, 0x3F803F80u, 0x3F803F80u};
    const bf16x8 ones = __builtin_bit_cast(bf16x8, onesu);

    const unsigned long long* arow = adj64 + (size_t)row * 64 + (w >> 1);
    const int bsh = (w & 1) * 32 + q * 8;          // bit offset within u64
    const int phys = 0;  (void)phys;
    unsigned long long au = arow[0];
    int cur = 0;

    for (int step = 0; step < 32; ++step) {
        unsigned long long an = 0;
        float4 nw2 = {0.f, 0.f, 0.f, 0.f};
        if (step < 31) {   // T14 issue-early: next tile + next wh2 + next adj word
            #pragma unroll
            for (int c = 0; c < 2; ++c)
                gl16(gsrc[c] + (step + 1) * 128,
                     ((unsigned short*)whTl[cur ^ 1]) + w * 1024 + c * 512);
            if (t < 32) nw2 = *(const float4*)&wh2p[(step + 1) * 128 + t * 4];
            an = arow[(step + 1) * 2];
        }

        {   // this wave's 32-j sub-slice of the current window (r10 kk-body)
            const int jl = w * 32 + q * 8;
            const int sl = ((w * 4 + q) ^ (r & 7)) * 8;   // XOR read map
            bf16x8 b0 = *(const bf16x8*)&whTl[cur][r][sl];
            bf16x8 b1 = *(const bf16x8*)&whTl[cur][16 + r][sl];
            unsigned int bits = (unsigned int)((au >> bsh) & 0xffull);
            float w2[8];
            *(float4*)&w2[0] = *(const float4*)&wh2t[cur][jl];
            *(float4*)&w2[4] = *(const float4*)&wh2t[cur][jl + 4];

            float p[8];
            #pragma unroll
            for (int b = 0; b < 8; ++b) {
                float u = wh1m + w2[b];                  // s - m   (s>0 case)
                float tv = fmaf(GAT_ALPHA, w2[b], c2);   // a*s - m (s<0 case)
                float s = fmaxf(u, tv);                  // lrelu(s) - m, <= 0
                float pe = EXP2F(s);
                p[b] = (bits & (1u << b)) ? pe : 0.f;    // mask
            }
            u32x4 pk = { cvt_pk_bf16(p[0], p[1]), cvt_pk_bf16(p[2], p[3]),
                         cvt_pk_bf16(p[4], p[5]), cvt_pk_bf16(p[6], p[7]) };
            bf16x8 af = __builtin_bit_cast(bf16x8, pk);
            acc0 = __builtin_amdgcn_mfma_f32_16x16x32_bf16(af, b0, acc0, 0, 0, 0);
            acc1 = __builtin_amdgcn_mfma_f32_16x16x32_bf16(af, b1, acc1, 0, 0, 0);
            accd = __builtin_amdgcn_mfma_f32_16x16x32_bf16(af, ones, accd, 0, 0, 0);
        }

        if (step < 31 && t < 32) *(float4*)&wh2t[cur ^ 1][t * 4] = nw2;  // T14 write-late
        __syncthreads();   // next stage drained + all waves done with buf[cur]
        au = an;
        cur ^= 1;
    }

    // combine the 4 j-slices (r5-validated): waves 1-3 publish, wave 0 adds.
    // red overlaid on dead whTl (9.2KB <= 16KB).
    f32x4 (*red)[64][3] = (f32x4(*)[64][3])whTl;
    if (w != 0) {
        red[w - 1][lane][0] = acc0;
        red[w - 1][lane][1] = acc1;
        red[w - 1][lane][2] = accd;
    }
    __syncthreads();
    if (w == 0) {
        #pragma unroll
        for (int jj = 0; jj < 3; ++jj) {
            acc0 += red[jj][lane][0];
            acc1 += red[jj][lane][1];
            accd += red[jj][lane][2];
        }
        // C/D layout (m89-verified): lane holds D[4q+i][r]
        #pragma unroll
        for (int i = 0; i < 4; ++i) {
            float inv = 1.0f / accd[i];
            int orow = rowbase + 4 * q + i;
            out[(size_t)orow * 256 + head * 32 + r]      = acc0[i] * inv;
            out[(size_t)orow * 256 + head * 32 + 16 + r] = acc1[i] * inv;
        }
    }
}

extern "C" void kernel_launch(void* const* d_in, const int* in_sizes, int n_in,
                              void* d_out, int out_size, void* d_ws, size_t ws_size,
                              hipStream_t stream) {
    const float* h   = (const float*)d_in[0];
    const int*   adj = (const int*)d_in[1];
    const float* W   = (const float*)d_in[2];
    const float* a   = (const float*)d_in[3];
    float* out = (float*)d_out;

    char* ws = (char*)d_ws;
    unsigned long long* packed = (unsigned long long*)ws;                        // 2 MB
    float* wh1s = (float*)(ws + (2 << 20));                                      // 128 KB
    float* wh2s = (float*)(ws + (2 << 20) + (128 << 10));                        // 128 KB
    unsigned short* whT  = (unsigned short*)(ws + (2 << 20) + (256 << 10));      // 2 MB
    unsigned short* wbfT = (unsigned short*)(ws + (4 << 20) + (256 << 10));      // 128 KB

    const int nwords = 4096 * 64;
    k_pack_adj<<<nwords * 64 / 256, 256, 0, stream>>>(adj, packed, nwords);
    k_cvtW<<<32, 256, 0, stream>>>(W, wbfT);
    k_wh2<<<dim3(64, 8), 256, 0, stream>>>(h, wbfT, a, wh1s, wh2s, whT);
    k_attn<<<dim3(256, 8), 256, 0, stream>>>(packed, wh1s, wh2s, whT, out);
}